// Round 8
// baseline (274.461 us; speedup 1.0000x reference)
//
#include <hip/hip_runtime.h>

#define BB 8
#define CC 128
#define NN 4096   // H*W = 64*64

typedef __bf16 bf16x8_t __attribute__((ext_vector_type(8)));
typedef unsigned short u16x8 __attribute__((ext_vector_type(8)));
typedef float f32x4 __attribute__((ext_vector_type(4)));
typedef float f32x16 __attribute__((ext_vector_type(16)));
typedef unsigned int u32x4 __attribute__((ext_vector_type(4)));
typedef __attribute__((address_space(1))) const unsigned int gu32;
typedef __attribute__((address_space(3))) unsigned int lu32;

#define KSCALE 0.12753262456033348f   // (1/sqrt(128)) * log2(e)

__device__ __forceinline__ unsigned short f2bf(float f) {
  unsigned int u = __builtin_bit_cast(unsigned int, f);
  u += 0x7fffu + ((u >> 16) & 1u);          // RNE
  return (unsigned short)(u >> 16);
}

__device__ __forceinline__ float bf2f(unsigned short s) {
  unsigned int u = ((unsigned int)s) << 16;
  return __builtin_bit_cast(float, u);
}

__device__ __forceinline__ unsigned int cvt_pk_bf16(float lo, float hi) {
  unsigned int r;
  asm("v_cvt_pk_bf16_f32 %0, %1, %2" : "=v"(r) : "v"(lo), "v"(hi));
  return r;
}

__device__ __forceinline__ f32x4 mfma16(u16x8 a, u16x8 b, f32x4 c) {
  return __builtin_amdgcn_mfma_f32_16x16x32_bf16(
      __builtin_bit_cast(bf16x8_t, a), __builtin_bit_cast(bf16x8_t, b), c, 0, 0, 0);
}

__device__ __forceinline__ f32x16 mfma32(u16x8 a, u16x8 b, f32x16 c) {
  return __builtin_amdgcn_mfma_f32_32x32x16_bf16(
      __builtin_bit_cast(bf16x8_t, a), __builtin_bit_cast(bf16x8_t, b), c, 0, 0, 0);
}

// ---------------------------------------------------------------------------
// Kernel 0: prep.  Blocks 0..63: Wq*KSCALE, Wv -> bf16.  Block 64: csk[c]=sum_o Wk[o][c]
// ---------------------------------------------------------------------------
__global__ void prep(const float* __restrict__ Wq, const float* __restrict__ Wv,
                     const float* __restrict__ Wk,
                     unsigned short* __restrict__ Qwb, unsigned short* __restrict__ Vwb,
                     float* __restrict__ csk) {
  if (blockIdx.x < 64) {
    const int i = blockIdx.x * 256 + threadIdx.x;
    Qwb[i] = f2bf(Wq[i] * KSCALE);
    Vwb[i] = f2bf(Wv[i]);
  } else if (threadIdx.x < CC) {
    const int c = threadIdx.x;
    float s = 0.f;
    for (int o = 0; o < CC; ++o) s += Wk[(size_t)o * CC + c];
    csk[c] = s;
  }
}

// ---------------------------------------------------------------------------
// Kernel 1: QKV projection (proven).
//  Q[b][n][o] = (x.Wq^T + bq) * KSCALE   bf16 pixel-major
//  K[b][n][c] =  x[c][n]*csk[c] + bk[c]  bf16 pixel-major
//  V[b][o][n] =  x.Wv^T + bv             bf16 channel-major
// ---------------------------------------------------------------------------
__global__ __launch_bounds__(256, 2) void qkv_proj(
    const float* __restrict__ x,
    const unsigned short* __restrict__ Qwb, const float* __restrict__ bq,
    const float* __restrict__ csk, const float* __restrict__ bk,
    const unsigned short* __restrict__ Vwb, const float* __restrict__ bv,
    unsigned short* __restrict__ Q,
    unsigned short* __restrict__ K,
    unsigned short* __restrict__ V)
{
  const int b  = blockIdx.x & 7;
  const int n0 = (blockIdx.x >> 3) << 6;
  const int t  = threadIdx.x;
  const int lane = t & 63;
  const int w  = t >> 6;
  const int lq = lane & 15;
  const int g  = lane >> 4;

  __shared__ unsigned short xs[64][136];
  __shared__ unsigned short ks[64][136];
  __shared__ unsigned short vs[128][72];

  {
    const int n = t & 63;
    const float* xp = x + (size_t)b * (CC * NN) + n0 + n;
    for (int c = t >> 6; c < CC; c += 4) {
      const float xv = xp[(size_t)c * NN];
      xs[n][c] = f2bf(xv);
      ks[n][c] = f2bf(xv * csk[c] + bk[c]);
    }
  }
  __syncthreads();

  u16x8 a[4];
  {
    const unsigned short* ap = &xs[w * 16 + lq][g * 8];
    for (int ksl = 0; ksl < 4; ++ksl) a[ksl] = *(const u16x8*)(ap + ksl * 32);
  }

  for (int ot = 0; ot < 8; ++ot) {
    f32x4 aq = {0.f,0.f,0.f,0.f}, av = {0.f,0.f,0.f,0.f};
    const int o = ot * 16 + lq;
    const unsigned short* wq = Qwb + (size_t)o * CC + g * 8;
    const unsigned short* wv = Vwb + (size_t)o * CC + g * 8;
    for (int ksl = 0; ksl < 4; ++ksl) {
      aq = mfma16(a[ksl], *(const u16x8*)(wq + ksl * 32), aq);
      av = mfma16(a[ksl], *(const u16x8*)(wv + ksl * 32), av);
    }
    const float bqv = bq[o] * KSCALE, bvv = bv[o];
    for (int r = 0; r < 4; ++r) {
      const int nl = w * 16 + g * 4 + r;
      Q[((size_t)b * NN + n0 + nl) * CC + o] = f2bf(aq[r] + bqv);
      vs[o][nl] = f2bf(av[r] + bvv);
    }
  }
  __syncthreads();

  {
    unsigned short* kout = K + ((size_t)b * NN + n0) * CC;
    for (int i = t; i < 64 * 16; i += 256) {
      const int n = i >> 4, oc = (i & 15) * 8;
      *(uint4*)(kout + (size_t)n * CC + oc) = *(const uint4*)&ks[n][oc];
    }
  }
  {
    unsigned short* vout = V + (size_t)b * (CC * NN) + n0;
    for (int i = t; i < 128 * 32; i += 256) {
      const int c  = i >> 5;
      const int np = (i & 31) << 1;
      *(unsigned int*)(vout + (size_t)c * NN + np) = *(const unsigned int*)&vs[c][np];
    }
  }
}

// ---------------------------------------------------------------------------
// Kernel 2: flash attention partials, 32x32x16 MFMA, KV split 4-way.
// 1024 blocks = 4/CU = 16 waves/CU. Zero-conflict swizzled LDS (round-7 layout).
// Two independent QK^T accumulation chains + tree-max + early V-fragment issue
// shorten the per-tile serial chain. Nontemporal partial stores keep K/V/Q in L2.
// ---------------------------------------------------------------------------
__global__ __launch_bounds__(256, 4) void flash_attn(
    const unsigned short* __restrict__ Q,
    const unsigned short* __restrict__ K,
    const unsigned short* __restrict__ V,
    float* __restrict__ PO0,             // split 0: fp32 normalized partial (d_out)
    unsigned short* __restrict__ PO123,  // splits 1..3: bf16 normalized partials
    float2* __restrict__ PML)            // [4][B][N]
{
  const int bid = blockIdx.x;
  const int b   = bid & 7;               // batch -> XCD-local K/V/Q
  const int qb  = (bid >> 3) & 31;
  const int sp  = bid >> 8;              // KV quarter 0..3
  const int kv0 = sp << 10;              // 1024 keys per quarter
  const int t   = threadIdx.x;
  const int lane = t & 63;
  const int w   = t >> 6;                // wave 0..3, 32 q-rows each
  const int cl  = lane & 31;
  const int hi  = lane >> 5;
  const int q0w = (qb << 7) + (w << 5);

  __shared__ unsigned short KtL[2][32 * 128];   // 8KB/buf: [key][c], (row&15)<<4 swz
  __shared__ unsigned short VlL[2][32 * 128];   // 8KB/buf: [c>>2][(c&3)*64+key*2], swz

  // Q B-frags: col q = cl, k-slice = ks*16 + hi*8
  u16x8 qf[8];
  {
    const unsigned short* qp = Q + ((size_t)b * NN + q0w + cl) * CC + hi * 8;
    #pragma unroll
    for (int ks = 0; ks < 8; ++ks) qf[ks] = *(const u16x8*)(qp + ks * 16);
  }

  // ---- staging offsets (pre-inverse-swizzled global source, linear LDS dest) ----
  const char* kgb = (const char*)(K + (size_t)b * NN * CC);   // 256B rows
  const char* vgb = (const char*)(V + (size_t)b * CC * NN);   // 8192B rows
  int soK[2], soV[2], voC[2];
  #pragma unroll
  for (int j = 0; j < 2; ++j) {
    const int a = t * 16 + j * 4096;
    const int row = a >> 8;                    // 0..31
    const int L = a & 255;
    const int offK = L ^ ((row & 15) << 4);
    soK[j] = (a & ~255) | offK;
    const int offV = L ^ ((row & 15) << 4);
    const int jj = offV >> 6;                  // channel-in-row 0..3
    voC[j] = (row * 4 + jj) * (NN * 2);
    soV[j] = offV & 63;                        // key-byte within tile row
  }
  const int p0 = t * 16;

  #define STAGE(nb, kv) do {                                                      \
    const char* kg_ = kgb + ((size_t)(kv) << 8);                                  \
    const char* vg_ = vgb + ((size_t)(kv) << 1);                                  \
    __builtin_amdgcn_global_load_lds((gu32*)(kg_ + soK[0]),                       \
        (lu32*)((char*)KtL + (nb) * 8192 + p0), 16, 0, 0);                        \
    __builtin_amdgcn_global_load_lds((gu32*)(kg_ + soK[1]),                       \
        (lu32*)((char*)KtL + (nb) * 8192 + p0 + 4096), 16, 0, 0);                 \
    __builtin_amdgcn_global_load_lds((gu32*)(vg_ + voC[0] + soV[0]),              \
        (lu32*)((char*)VlL + (nb) * 8192 + p0), 16, 0, 0);                        \
    __builtin_amdgcn_global_load_lds((gu32*)(vg_ + voC[1] + soV[1]),              \
        (lu32*)((char*)VlL + (nb) * 8192 + p0 + 4096), 16, 0, 0);                 \
  } while (0)

  f32x16 oacc[4];
  #pragma unroll
  for (int i = 0; i < 4; ++i)
    #pragma unroll
    for (int r = 0; r < 16; ++r) oacc[i][r] = 0.f;
  float m_run = -1e30f, l_run = 0.f;

  // ---- per-lane read offsets ----
  const int swzK = (cl & 15) << 4;             // K read: row = cl
  int voffs[8];                                 // V read: [ct][kk]
  {
    const int rl = cl >> 2, j = cl & 3;
    #pragma unroll
    for (int ct = 0; ct < 4; ++ct)
      #pragma unroll
      for (int kk = 0; kk < 2; ++kk)
        voffs[ct * 2 + kk] = ct * 2048 + rl * 256 +
            (((j * 64 + kk * 32 + hi * 16) ^ (rl << 4)) ^ ((ct & 1) << 7));
  }

  STAGE(0, kv0);

  for (int tt = 0; tt < 32; ++tt) {
    const int cur = tt & 1;
    if (tt < 31) {
      STAGE(cur ^ 1, kv0 + (tt + 1) * 32);
      asm volatile("s_waitcnt vmcnt(4)" ::: "memory");
    } else {
      asm volatile("s_waitcnt vmcnt(0)" ::: "memory");
    }
    __builtin_amdgcn_s_barrier();

    // ---- S^T = K . Q^T : two independent 4-deep mfma32 chains ----
    const char* kb = (const char*)KtL + cur * 8192 + cl * 256;
    const char* vbb = (const char*)VlL + cur * 8192;
    f32x16 s_a, s_b;
    #pragma unroll
    for (int r = 0; r < 16; ++r) { s_a[r] = 0.f; s_b[r] = 0.f; }
    __builtin_amdgcn_s_setprio(1);
    #pragma unroll
    for (int ks = 0; ks < 4; ++ks) {
      u16x8 kfa = *(const u16x8*)(kb + (((2 * ks) * 32 + hi * 16) ^ swzK));
      s_a = mfma32(kfa, qf[2 * ks], s_a);
      u16x8 kfb = *(const u16x8*)(kb + (((2 * ks + 1) * 32 + hi * 16) ^ swzK));
      s_b = mfma32(kfb, qf[2 * ks + 1], s_b);
    }
    __builtin_amdgcn_s_setprio(0);

    // early-issue V fragments for ct=0 (independent of softmax)
    u16x8 vf00 = *(const u16x8*)(vbb + voffs[0]);
    u16x8 vf01 = *(const u16x8*)(vbb + voffs[1]);

    f32x16 s = s_a + s_b;

    // ---- online softmax for q = cl (tree max, defer-max T13) ----
    float mx[8];
    #pragma unroll
    for (int r = 0; r < 8; ++r) mx[r] = fmaxf(s[r], s[r + 8]);
    #pragma unroll
    for (int r = 0; r < 4; ++r) mx[r] = fmaxf(mx[r], mx[r + 4]);
    mx[0] = fmaxf(mx[0], mx[2]); mx[1] = fmaxf(mx[1], mx[3]);
    float pm = fmaxf(mx[0], mx[1]);
    pm = fmaxf(pm, __shfl_xor(pm, 32));
    if (!__all(pm - m_run <= 8.0f)) {
      const float m_new = fmaxf(m_run, pm);
      const float alpha = exp2f(m_run - m_new);
      l_run *= alpha;
      #pragma unroll
      for (int i = 0; i < 4; ++i)
        #pragma unroll
        for (int r = 0; r < 16; ++r) oacc[i][r] *= alpha;
      m_run = m_new;
    }
    float e[16];
    #pragma unroll
    for (int r = 0; r < 16; ++r) e[r] = exp2f(s[r] - m_run);
    float l0 = (e[0] + e[1]) + (e[2] + e[3]);
    float l1 = (e[4] + e[5]) + (e[6] + e[7]);
    float l2 = (e[8] + e[9]) + (e[10] + e[11]);
    float l3 = (e[12] + e[13]) + (e[14] + e[15]);
    float lsum = (l0 + l1) + (l2 + l3);
    lsum += __shfl_xor(lsum, 32);
    l_run += lsum;

    // ---- P -> bf16 B-frags in-register (T12) ----
    unsigned pk0 = cvt_pk_bf16(e[0], e[1]),   pk1 = cvt_pk_bf16(e[2], e[3]);
    unsigned pk2 = cvt_pk_bf16(e[4], e[5]),   pk3 = cvt_pk_bf16(e[6], e[7]);
    unsigned pk4 = cvt_pk_bf16(e[8], e[9]),   pk5 = cvt_pk_bf16(e[10], e[11]);
    unsigned pk6 = cvt_pk_bf16(e[12], e[13]), pk7 = cvt_pk_bf16(e[14], e[15]);
    asm("v_permlane32_swap_b32 %0, %1" : "+v"(pk0), "+v"(pk2));
    asm("v_permlane32_swap_b32 %0, %1" : "+v"(pk1), "+v"(pk3));
    asm("v_permlane32_swap_b32 %0, %1" : "+v"(pk4), "+v"(pk6));
    asm("v_permlane32_swap_b32 %0, %1" : "+v"(pk5), "+v"(pk7));
    u32x4 pw0 = {pk0, pk1, pk2, pk3};
    u32x4 pw1 = {pk4, pk5, pk6, pk7};
    const u16x8 pf0 = __builtin_bit_cast(u16x8, pw0);   // keys 0..15 slice
    const u16x8 pf1 = __builtin_bit_cast(u16x8, pw1);   // keys 16..31 slice

    // ---- O^T += V^T . P^T ----
    __builtin_amdgcn_s_setprio(1);
    oacc[0] = mfma32(vf00, pf0, oacc[0]);
    oacc[0] = mfma32(vf01, pf1, oacc[0]);
    #pragma unroll
    for (int ct = 1; ct < 4; ++ct) {
      u16x8 vf0 = *(const u16x8*)(vbb + voffs[ct * 2 + 0]);
      oacc[ct] = mfma32(vf0, pf0, oacc[ct]);
      u16x8 vf1 = *(const u16x8*)(vbb + voffs[ct * 2 + 1]);
      oacc[ct] = mfma32(vf1, pf1, oacc[ct]);
    }
    __builtin_amdgcn_s_setprio(0);
    asm volatile("s_waitcnt lgkmcnt(0)" ::: "memory");
    __builtin_amdgcn_s_barrier();
  }
  #undef STAGE

  // ---- epilogue: normalized partials, channel-major, nontemporal ----
  const float rinv = 1.0f / l_run;
  const int n = q0w + cl;
  if (sp == 0) {
    float* po = PO0 + (size_t)b * (CC * NN);
    #pragma unroll
    for (int ct = 0; ct < 4; ++ct)
      #pragma unroll
      for (int r = 0; r < 16; ++r) {
        const int c = ct * 32 + (r & 3) + 8 * (r >> 2) + 4 * hi;
        __builtin_nontemporal_store(oacc[ct][r] * rinv, &po[(size_t)c * NN + n]);
      }
  } else {
    unsigned short* po = PO123 + (size_t)(sp - 1) * (BB * CC * NN) + (size_t)b * (CC * NN);
    #pragma unroll
    for (int ct = 0; ct < 4; ++ct)
      #pragma unroll
      for (int r = 0; r < 16; ++r) {
        const int c = ct * 32 + (r & 3) + 8 * (r >> 2) + 4 * hi;
        const unsigned short v = f2bf(oacc[ct][r] * rinv);
        __builtin_nontemporal_store(v, &po[(size_t)c * NN + n]);
      }
  }
  if (hi == 0) PML[((size_t)sp * BB + b) * NN + n] = float2{m_run, l_run};
}

// ---------------------------------------------------------------------------
// Kernel 3: combine 4 KV-quarter partials + residual.
// out = x + sum_s wgt_s*o_s, wgt_s = l_s*exp2(m_s-M)/sum. PML read once/thread.
// ---------------------------------------------------------------------------
__global__ __launch_bounds__(256) void combine(
    const float* __restrict__ x,
    const unsigned short* __restrict__ PO123,
    const float2* __restrict__ PML,
    float* __restrict__ out)                    // in: PO0 fp32, out: final
{
  const int bid = blockIdx.x;                   // 512 = 8 b x 64 n-chunks
  const int b = bid & 7;
  const int n = ((bid >> 3) << 6) + (threadIdx.x & 63);
  const int cq = threadIdx.x >> 6;
  float m[4], l[4];
  #pragma unroll
  for (int s = 0; s < 4; ++s) {
    const float2 ml = PML[((size_t)s * BB + b) * NN + n];
    m[s] = ml.x; l[s] = ml.y;
  }
  const float M = fmaxf(fmaxf(m[0], m[1]), fmaxf(m[2], m[3]));
  float wgt[4];
  #pragma unroll
  for (int s = 0; s < 4; ++s) wgt[s] = l[s] * exp2f(m[s] - M);
  const float inv = 1.0f / ((wgt[0] + wgt[1]) + (wgt[2] + wgt[3]));
  #pragma unroll
  for (int s = 0; s < 4; ++s) wgt[s] *= inv;

  const size_t base = (size_t)b * (CC * NN) + n;
  const unsigned short* po1 = PO123;
  const unsigned short* po2 = PO123 + (size_t)BB * CC * NN;
  const unsigned short* po3 = PO123 + (size_t)2 * BB * CC * NN;
  for (int c = cq; c < CC; c += 4) {
    const size_t idx = base + (size_t)c * NN;
    float acc = wgt[0] * __builtin_nontemporal_load(&out[idx]);
    acc += wgt[1] * bf2f(__builtin_nontemporal_load(&po1[idx]));
    acc += wgt[2] * bf2f(__builtin_nontemporal_load(&po2[idx]));
    acc += wgt[3] * bf2f(__builtin_nontemporal_load(&po3[idx]));
    out[idx] = x[idx] + acc;
  }
}

extern "C" void kernel_launch(void* const* d_in, const int* in_sizes, int n_in,
                              void* d_out, int out_size, void* d_ws, size_t ws_size,
                              hipStream_t stream) {
  (void)in_sizes; (void)n_in; (void)out_size; (void)ws_size;
  const float* x  = (const float*)d_in[0];
  const float* Wq = (const float*)d_in[1];
  const float* bq = (const float*)d_in[2];
  const float* Wk = (const float*)d_in[3];
  const float* bk = (const float*)d_in[4];
  const float* Wv = (const float*)d_in[5];
  const float* bv = (const float*)d_in[6];

  unsigned short* Q     = (unsigned short*)d_ws;                  // 8 MB
  unsigned short* K     = Q + (size_t)BB * NN * CC;               // 8 MB
  unsigned short* V     = K + (size_t)BB * NN * CC;               // 8 MB
  unsigned short* PO123 = V + (size_t)BB * NN * CC;               // 24 MB (3 bf16 partials)
  float2* PML           = (float2*)(PO123 + (size_t)3 * BB * CC * NN); // 1 MB
  unsigned short* Qwb   = (unsigned short*)(PML + (size_t)4 * BB * NN); // 32 KB
  unsigned short* Vwb   = Qwb + (size_t)CC * CC;                  // 32 KB
  float* csk = (float*)(Vwb + (size_t)CC * CC);                   // 512 B
  float* out = (float*)d_out;                                     // also fp32 partial 0

  prep<<<dim3(65), dim3(256), 0, stream>>>(Wq, Wv, Wk, Qwb, Vwb, csk);
  qkv_proj<<<dim3(BB * (NN / 64)), dim3(256), 0, stream>>>(x, Qwb, bq, csk, bk, Vwb, bv, Q, K, V);
  flash_attn<<<dim3(BB * 32 * 4), dim3(256), 0, stream>>>(Q, K, V, out, PO123, PML);
  combine<<<dim3(BB * (NN / 64)), dim3(256), 0, stream>>>(x, PO123, PML, out);
}

// Round 9
// 226.250 us; speedup vs baseline: 1.2131x; 1.2131x over previous
//
#include <hip/hip_runtime.h>

#define BB 8
#define CC 128
#define NN 4096   // H*W = 64*64

typedef __bf16 bf16x8_t __attribute__((ext_vector_type(8)));
typedef unsigned short u16x8 __attribute__((ext_vector_type(8)));
typedef float f32x4 __attribute__((ext_vector_type(4)));
typedef float f32x16 __attribute__((ext_vector_type(16)));
typedef unsigned int u32x4 __attribute__((ext_vector_type(4)));
typedef __attribute__((address_space(1))) const unsigned int gu32;
typedef __attribute__((address_space(3))) unsigned int lu32;

#define KSCALE 0.12753262456033348f   // (1/sqrt(128)) * log2(e)

__device__ __forceinline__ unsigned short f2bf(float f) {
  unsigned int u = __builtin_bit_cast(unsigned int, f);
  u += 0x7fffu + ((u >> 16) & 1u);          // RNE
  return (unsigned short)(u >> 16);
}

__device__ __forceinline__ float bf2f(unsigned short s) {
  unsigned int u = ((unsigned int)s) << 16;
  return __builtin_bit_cast(float, u);
}

__device__ __forceinline__ unsigned int cvt_pk_bf16(float lo, float hi) {
  unsigned int r;
  asm("v_cvt_pk_bf16_f32 %0, %1, %2" : "=v"(r) : "v"(lo), "v"(hi));
  return r;
}

__device__ __forceinline__ f32x4 mfma16(u16x8 a, u16x8 b, f32x4 c) {
  return __builtin_amdgcn_mfma_f32_16x16x32_bf16(
      __builtin_bit_cast(bf16x8_t, a), __builtin_bit_cast(bf16x8_t, b), c, 0, 0, 0);
}

__device__ __forceinline__ f32x16 mfma32(u16x8 a, u16x8 b, f32x16 c) {
  return __builtin_amdgcn_mfma_f32_32x32x16_bf16(
      __builtin_bit_cast(bf16x8_t, a), __builtin_bit_cast(bf16x8_t, b), c, 0, 0, 0);
}

// ---------------------------------------------------------------------------
// Kernel 0: prep.  Blocks 0..63: Wq*KSCALE, Wv -> bf16.  Block 64: csk[c]=sum_o Wk[o][c]
// ---------------------------------------------------------------------------
__global__ void prep(const float* __restrict__ Wq, const float* __restrict__ Wv,
                     const float* __restrict__ Wk,
                     unsigned short* __restrict__ Qwb, unsigned short* __restrict__ Vwb,
                     float* __restrict__ csk) {
  if (blockIdx.x < 64) {
    const int i = blockIdx.x * 256 + threadIdx.x;
    Qwb[i] = f2bf(Wq[i] * KSCALE);
    Vwb[i] = f2bf(Wv[i]);
  } else if (threadIdx.x < CC) {
    const int c = threadIdx.x;
    float s = 0.f;
    for (int o = 0; o < CC; ++o) s += Wk[(size_t)o * CC + c];
    csk[c] = s;
  }
}

// ---------------------------------------------------------------------------
// Kernel 1: QKV projection (proven).
//  Q[b][n][o] = (x.Wq^T + bq) * KSCALE   bf16 pixel-major
//  K[b][n][c] =  x[c][n]*csk[c] + bk[c]  bf16 pixel-major
//  V[b][o][n] =  x.Wv^T + bv             bf16 channel-major
// ---------------------------------------------------------------------------
__global__ __launch_bounds__(256, 2) void qkv_proj(
    const float* __restrict__ x,
    const unsigned short* __restrict__ Qwb, const float* __restrict__ bq,
    const float* __restrict__ csk, const float* __restrict__ bk,
    const unsigned short* __restrict__ Vwb, const float* __restrict__ bv,
    unsigned short* __restrict__ Q,
    unsigned short* __restrict__ K,
    unsigned short* __restrict__ V)
{
  const int b  = blockIdx.x & 7;
  const int n0 = (blockIdx.x >> 3) << 6;
  const int t  = threadIdx.x;
  const int lane = t & 63;
  const int w  = t >> 6;
  const int lq = lane & 15;
  const int g  = lane >> 4;

  __shared__ unsigned short xs[64][136];
  __shared__ unsigned short ks[64][136];
  __shared__ unsigned short vs[128][72];

  {
    const int n = t & 63;
    const float* xp = x + (size_t)b * (CC * NN) + n0 + n;
    for (int c = t >> 6; c < CC; c += 4) {
      const float xv = xp[(size_t)c * NN];
      xs[n][c] = f2bf(xv);
      ks[n][c] = f2bf(xv * csk[c] + bk[c]);
    }
  }
  __syncthreads();

  u16x8 a[4];
  {
    const unsigned short* ap = &xs[w * 16 + lq][g * 8];
    for (int ksl = 0; ksl < 4; ++ksl) a[ksl] = *(const u16x8*)(ap + ksl * 32);
  }

  for (int ot = 0; ot < 8; ++ot) {
    f32x4 aq = {0.f,0.f,0.f,0.f}, av = {0.f,0.f,0.f,0.f};
    const int o = ot * 16 + lq;
    const unsigned short* wq = Qwb + (size_t)o * CC + g * 8;
    const unsigned short* wv = Vwb + (size_t)o * CC + g * 8;
    for (int ksl = 0; ksl < 4; ++ksl) {
      aq = mfma16(a[ksl], *(const u16x8*)(wq + ksl * 32), aq);
      av = mfma16(a[ksl], *(const u16x8*)(wv + ksl * 32), av);
    }
    const float bqv = bq[o] * KSCALE, bvv = bv[o];
    for (int r = 0; r < 4; ++r) {
      const int nl = w * 16 + g * 4 + r;
      Q[((size_t)b * NN + n0 + nl) * CC + o] = f2bf(aq[r] + bqv);
      vs[o][nl] = f2bf(av[r] + bvv);
    }
  }
  __syncthreads();

  {
    unsigned short* kout = K + ((size_t)b * NN + n0) * CC;
    for (int i = t; i < 64 * 16; i += 256) {
      const int n = i >> 4, oc = (i & 15) * 8;
      *(uint4*)(kout + (size_t)n * CC + oc) = *(const uint4*)&ks[n][oc];
    }
  }
  {
    unsigned short* vout = V + (size_t)b * (CC * NN) + n0;
    for (int i = t; i < 128 * 32; i += 256) {
      const int c  = i >> 5;
      const int np = (i & 31) << 1;
      *(unsigned int*)(vout + (size_t)c * NN + np) = *(const unsigned int*)&vs[c][np];
    }
  }
}

// ---------------------------------------------------------------------------
// Kernel 2: flash attention partials, 32x32x16 MFMA, KV split 4-way.
// 512 blocks x 512 thr (8 waves x 32 q = 256 q-rows/block) = 2 blocks/CU =
// 16 waves/CU = 4/SIMD.  One shared staging pipeline per block: each 32-key
// tile staged once serves 8 waves (halves K/V re-read stream vs 128q blocks).
// Zero-conflict swizzled LDS; in-register P (cvt_pk + permlane32_swap).
// NO nontemporal anywhere (round-8 lesson: NT wrecks XCD L2 residency).
// ---------------------------------------------------------------------------
__global__ __launch_bounds__(512, 4) void flash_attn(
    const unsigned short* __restrict__ Q,
    const unsigned short* __restrict__ K,
    const unsigned short* __restrict__ V,
    float* __restrict__ PO0,             // split 0: fp32 normalized partial (d_out)
    unsigned short* __restrict__ PO123,  // splits 1..3: bf16 normalized partials
    float2* __restrict__ PML)            // [4][B][N]
{
  const int bid = blockIdx.x;
  const int b   = bid & 7;               // batch -> XCD-local K/V/Q
  const int qb  = (bid >> 3) & 15;       // 16 q-blocks of 256 rows
  const int sp  = bid >> 7;              // KV quarter 0..3
  const int kv0 = sp << 10;              // 1024 keys per quarter
  const int t   = threadIdx.x;
  const int lane = t & 63;
  const int w   = t >> 6;                // wave 0..7, 32 q-rows each
  const int cl  = lane & 31;
  const int hi  = lane >> 5;
  const int q0w = (qb << 8) + (w << 5);

  __shared__ unsigned short KtL[2][32 * 128];   // 8KB/buf: [key][c], (row&15)<<4 swz
  __shared__ unsigned short VlL[2][32 * 128];   // 8KB/buf: [c>>2][(c&3)*64+key*2], swz

  // Q B-frags: col q = cl, k-slice = ks*16 + hi*8
  u16x8 qf[8];
  {
    const unsigned short* qp = Q + ((size_t)b * NN + q0w + cl) * CC + hi * 8;
    #pragma unroll
    for (int ks = 0; ks < 8; ++ks) qf[ks] = *(const u16x8*)(qp + ks * 16);
  }

  // ---- staging offsets (pre-inverse-swizzled source, linear LDS dest) ----
  // 512 threads x 16B = 8KB = one full K (or V) tile per issue.
  const char* kgb = (const char*)(K + (size_t)b * NN * CC);   // 256B rows
  const char* vgb = (const char*)(V + (size_t)b * CC * NN);   // 8192B rows
  const int a0  = t * 16;
  const int row = a0 >> 8;                     // 0..31
  const int L   = a0 & 255;
  const int off = L ^ ((row & 15) << 4);
  const int soK = (a0 & ~255) | off;
  const int jj  = off >> 6;                    // channel-in-row 0..3
  const int voC = (row * 4 + jj) * (NN * 2);
  const int soV = off & 63;                    // key-byte within tile row
  const int p0  = a0;

  #define STAGE(nb, kv) do {                                                      \
    const char* kg_ = kgb + ((size_t)(kv) << 8);                                  \
    const char* vg_ = vgb + ((size_t)(kv) << 1);                                  \
    __builtin_amdgcn_global_load_lds((gu32*)(kg_ + soK),                          \
        (lu32*)((char*)KtL + (nb) * 8192 + p0), 16, 0, 0);                        \
    __builtin_amdgcn_global_load_lds((gu32*)(vg_ + voC + soV),                    \
        (lu32*)((char*)VlL + (nb) * 8192 + p0), 16, 0, 0);                        \
  } while (0)

  f32x16 oacc[4];
  #pragma unroll
  for (int i = 0; i < 4; ++i)
    #pragma unroll
    for (int r = 0; r < 16; ++r) oacc[i][r] = 0.f;
  float m_run = -1e30f, l_run = 0.f;

  // ---- per-lane read offsets ----
  const int swzK = (cl & 15) << 4;             // K read: row = cl
  int voffs[8];                                 // V read: [ct][kk]
  {
    const int rl = cl >> 2, j = cl & 3;
    #pragma unroll
    for (int ct = 0; ct < 4; ++ct)
      #pragma unroll
      for (int kk = 0; kk < 2; ++kk)
        voffs[ct * 2 + kk] = ct * 2048 + rl * 256 +
            (((j * 64 + kk * 32 + hi * 16) ^ (rl << 4)) ^ ((ct & 1) << 7));
  }

  STAGE(0, kv0);

  for (int tt = 0; tt < 32; ++tt) {
    const int cur = tt & 1;
    if (tt < 31) {
      STAGE(cur ^ 1, kv0 + (tt + 1) * 32);
      asm volatile("s_waitcnt vmcnt(2)" ::: "memory");   // current tile resident
    } else {
      asm volatile("s_waitcnt vmcnt(0)" ::: "memory");
    }
    __builtin_amdgcn_s_barrier();

    // ---- S^T = K . Q^T : two independent 4-deep mfma32 chains ----
    const char* kb = (const char*)KtL + cur * 8192 + cl * 256;
    const char* vbb = (const char*)VlL + cur * 8192;
    f32x16 s_a, s_b;
    #pragma unroll
    for (int r = 0; r < 16; ++r) { s_a[r] = 0.f; s_b[r] = 0.f; }
    __builtin_amdgcn_s_setprio(1);
    #pragma unroll
    for (int ks = 0; ks < 4; ++ks) {
      u16x8 kfa = *(const u16x8*)(kb + (((2 * ks) * 32 + hi * 16) ^ swzK));
      s_a = mfma32(kfa, qf[2 * ks], s_a);
      u16x8 kfb = *(const u16x8*)(kb + (((2 * ks + 1) * 32 + hi * 16) ^ swzK));
      s_b = mfma32(kfb, qf[2 * ks + 1], s_b);
    }
    __builtin_amdgcn_s_setprio(0);

    // early-issue V fragments for ct=0 (independent of softmax)
    u16x8 vf00 = *(const u16x8*)(vbb + voffs[0]);
    u16x8 vf01 = *(const u16x8*)(vbb + voffs[1]);

    f32x16 s = s_a + s_b;

    // ---- online softmax for q = cl (tree max, defer-max T13) ----
    float mx[8];
    #pragma unroll
    for (int r = 0; r < 8; ++r) mx[r] = fmaxf(s[r], s[r + 8]);
    #pragma unroll
    for (int r = 0; r < 4; ++r) mx[r] = fmaxf(mx[r], mx[r + 4]);
    mx[0] = fmaxf(mx[0], mx[2]); mx[1] = fmaxf(mx[1], mx[3]);
    float pm = fmaxf(mx[0], mx[1]);
    pm = fmaxf(pm, __shfl_xor(pm, 32));
    if (!__all(pm - m_run <= 8.0f)) {
      const float m_new = fmaxf(m_run, pm);
      const float alpha = exp2f(m_run - m_new);
      l_run *= alpha;
      #pragma unroll
      for (int i = 0; i < 4; ++i)
        #pragma unroll
        for (int r = 0; r < 16; ++r) oacc[i][r] *= alpha;
      m_run = m_new;
    }
    float e[16];
    #pragma unroll
    for (int r = 0; r < 16; ++r) e[r] = exp2f(s[r] - m_run);
    float l0 = (e[0] + e[1]) + (e[2] + e[3]);
    float l1 = (e[4] + e[5]) + (e[6] + e[7]);
    float l2 = (e[8] + e[9]) + (e[10] + e[11]);
    float l3 = (e[12] + e[13]) + (e[14] + e[15]);
    float lsum = (l0 + l1) + (l2 + l3);
    lsum += __shfl_xor(lsum, 32);
    l_run += lsum;

    // ---- P -> bf16 B-frags in-register (T12) ----
    unsigned pk0 = cvt_pk_bf16(e[0], e[1]),   pk1 = cvt_pk_bf16(e[2], e[3]);
    unsigned pk2 = cvt_pk_bf16(e[4], e[5]),   pk3 = cvt_pk_bf16(e[6], e[7]);
    unsigned pk4 = cvt_pk_bf16(e[8], e[9]),   pk5 = cvt_pk_bf16(e[10], e[11]);
    unsigned pk6 = cvt_pk_bf16(e[12], e[13]), pk7 = cvt_pk_bf16(e[14], e[15]);
    asm("v_permlane32_swap_b32 %0, %1" : "+v"(pk0), "+v"(pk2));
    asm("v_permlane32_swap_b32 %0, %1" : "+v"(pk1), "+v"(pk3));
    asm("v_permlane32_swap_b32 %0, %1" : "+v"(pk4), "+v"(pk6));
    asm("v_permlane32_swap_b32 %0, %1" : "+v"(pk5), "+v"(pk7));
    u32x4 pw0 = {pk0, pk1, pk2, pk3};
    u32x4 pw1 = {pk4, pk5, pk6, pk7};
    const u16x8 pf0 = __builtin_bit_cast(u16x8, pw0);   // keys 0..15 slice
    const u16x8 pf1 = __builtin_bit_cast(u16x8, pw1);   // keys 16..31 slice

    // ---- O^T += V^T . P^T ----
    __builtin_amdgcn_s_setprio(1);
    oacc[0] = mfma32(vf00, pf0, oacc[0]);
    oacc[0] = mfma32(vf01, pf1, oacc[0]);
    #pragma unroll
    for (int ct = 1; ct < 4; ++ct) {
      u16x8 vf0 = *(const u16x8*)(vbb + voffs[ct * 2 + 0]);
      oacc[ct] = mfma32(vf0, pf0, oacc[ct]);
      u16x8 vf1 = *(const u16x8*)(vbb + voffs[ct * 2 + 1]);
      oacc[ct] = mfma32(vf1, pf1, oacc[ct]);
    }
    __builtin_amdgcn_s_setprio(0);
    asm volatile("s_waitcnt lgkmcnt(0)" ::: "memory");
    __builtin_amdgcn_s_barrier();
  }
  #undef STAGE

  // ---- epilogue: normalized partials, channel-major (normal stores) ----
  const float rinv = 1.0f / l_run;
  const int n = q0w + cl;
  if (sp == 0) {
    float* po = PO0 + (size_t)b * (CC * NN);
    #pragma unroll
    for (int ct = 0; ct < 4; ++ct)
      #pragma unroll
      for (int r = 0; r < 16; ++r) {
        const int c = ct * 32 + (r & 3) + 8 * (r >> 2) + 4 * hi;
        po[(size_t)c * NN + n] = oacc[ct][r] * rinv;
      }
  } else {
    unsigned short* po = PO123 + (size_t)(sp - 1) * (BB * CC * NN) + (size_t)b * (CC * NN);
    #pragma unroll
    for (int ct = 0; ct < 4; ++ct)
      #pragma unroll
      for (int r = 0; r < 16; ++r) {
        const int c = ct * 32 + (r & 3) + 8 * (r >> 2) + 4 * hi;
        po[(size_t)c * NN + n] = f2bf(oacc[ct][r] * rinv);
      }
  }
  if (hi == 0) PML[((size_t)sp * BB + b) * NN + n] = float2{m_run, l_run};
}

// ---------------------------------------------------------------------------
// Kernel 3: combine 4 KV-quarter partials + residual.
// out = x + sum_s wgt_s*o_s, wgt_s = l_s*exp2(m_s-M)/sum. PML read once/thread.
// ---------------------------------------------------------------------------
__global__ __launch_bounds__(256) void combine(
    const float* __restrict__ x,
    const unsigned short* __restrict__ PO123,
    const float2* __restrict__ PML,
    float* __restrict__ out)                    // in: PO0 fp32, out: final
{
  const int bid = blockIdx.x;                   // 512 = 8 b x 64 n-chunks
  const int b = bid & 7;
  const int n = ((bid >> 3) << 6) + (threadIdx.x & 63);
  const int cq = threadIdx.x >> 6;
  float m[4], l[4];
  #pragma unroll
  for (int s = 0; s < 4; ++s) {
    const float2 ml = PML[((size_t)s * BB + b) * NN + n];
    m[s] = ml.x; l[s] = ml.y;
  }
  const float M = fmaxf(fmaxf(m[0], m[1]), fmaxf(m[2], m[3]));
  float wgt[4];
  #pragma unroll
  for (int s = 0; s < 4; ++s) wgt[s] = l[s] * exp2f(m[s] - M);
  const float inv = 1.0f / ((wgt[0] + wgt[1]) + (wgt[2] + wgt[3]));
  #pragma unroll
  for (int s = 0; s < 4; ++s) wgt[s] *= inv;

  const size_t base = (size_t)b * (CC * NN) + n;
  const unsigned short* po1 = PO123;
  const unsigned short* po2 = PO123 + (size_t)BB * CC * NN;
  const unsigned short* po3 = PO123 + (size_t)2 * BB * CC * NN;
  for (int c = cq; c < CC; c += 4) {
    const size_t idx = base + (size_t)c * NN;
    float acc = wgt[0] * out[idx];
    acc += wgt[1] * bf2f(po1[idx]);
    acc += wgt[2] * bf2f(po2[idx]);
    acc += wgt[3] * bf2f(po3[idx]);
    out[idx] = x[idx] + acc;
  }
}

extern "C" void kernel_launch(void* const* d_in, const int* in_sizes, int n_in,
                              void* d_out, int out_size, void* d_ws, size_t ws_size,
                              hipStream_t stream) {
  (void)in_sizes; (void)n_in; (void)out_size; (void)ws_size;
  const float* x  = (const float*)d_in[0];
  const float* Wq = (const float*)d_in[1];
  const float* bq = (const float*)d_in[2];
  const float* Wk = (const float*)d_in[3];
  const float* bk = (const float*)d_in[4];
  const float* Wv = (const float*)d_in[5];
  const float* bv = (const float*)d_in[6];

  unsigned short* Q     = (unsigned short*)d_ws;                  // 8 MB
  unsigned short* K     = Q + (size_t)BB * NN * CC;               // 8 MB
  unsigned short* V     = K + (size_t)BB * NN * CC;               // 8 MB
  unsigned short* PO123 = V + (size_t)BB * NN * CC;               // 24 MB (3 bf16 partials)
  float2* PML           = (float2*)(PO123 + (size_t)3 * BB * CC * NN); // 1 MB
  unsigned short* Qwb   = (unsigned short*)(PML + (size_t)4 * BB * NN); // 32 KB
  unsigned short* Vwb   = Qwb + (size_t)CC * CC;                  // 32 KB
  float* csk = (float*)(Vwb + (size_t)CC * CC);                   // 512 B
  float* out = (float*)d_out;                                     // also fp32 partial 0

  prep<<<dim3(65), dim3(256), 0, stream>>>(Wq, Wv, Wk, Qwb, Vwb, csk);
  qkv_proj<<<dim3(BB * (NN / 64)), dim3(256), 0, stream>>>(x, Qwb, bq, csk, bk, Vwb, bv, Q, K, V);
  flash_attn<<<dim3(BB * 16 * 4), dim3(512), 0, stream>>>(Q, K, V, out, PO123, PML);
  combine<<<dim3(BB * (NN / 64)), dim3(256), 0, stream>>>(x, PO123, PML, out);
}

// Round 10
// 145.527 us; speedup vs baseline: 1.8860x; 1.5547x over previous
//
#include <hip/hip_runtime.h>

#define BB 8
#define CC 128
#define NN 4096   // H*W = 64*64

typedef __bf16 bf16x8_t __attribute__((ext_vector_type(8)));
typedef unsigned short u16x8 __attribute__((ext_vector_type(8)));
typedef unsigned short u16x4 __attribute__((ext_vector_type(4)));
typedef float f32x4 __attribute__((ext_vector_type(4)));
typedef unsigned int u32x4 __attribute__((ext_vector_type(4)));
typedef __attribute__((address_space(1))) const unsigned int gu32;
typedef __attribute__((address_space(3))) unsigned int lu32;

#define KSCALE 0.12753262456033348f   // (1/sqrt(128)) * log2(e)

__device__ __forceinline__ unsigned short f2bf(float f) {
  unsigned int u = __builtin_bit_cast(unsigned int, f);
  u += 0x7fffu + ((u >> 16) & 1u);          // RNE
  return (unsigned short)(u >> 16);
}

__device__ __forceinline__ unsigned int cvt_pk_bf16(float lo, float hi) {
  unsigned int r;
  asm("v_cvt_pk_bf16_f32 %0, %1, %2" : "=v"(r) : "v"(lo), "v"(hi));
  return r;
}

__device__ __forceinline__ f32x4 mfma16(u16x8 a, u16x8 b, f32x4 c) {
  return __builtin_amdgcn_mfma_f32_16x16x32_bf16(
      __builtin_bit_cast(bf16x8_t, a), __builtin_bit_cast(bf16x8_t, b), c, 0, 0, 0);
}

// ---------------------------------------------------------------------------
// Kernel 0: prep.  Blocks 0..63: Wq*KSCALE, Wv -> bf16.  Block 64: csk[c]=sum_o Wk[o][c]
// ---------------------------------------------------------------------------
__global__ void prep(const float* __restrict__ Wq, const float* __restrict__ Wv,
                     const float* __restrict__ Wk,
                     unsigned short* __restrict__ Qwb, unsigned short* __restrict__ Vwb,
                     float* __restrict__ csk) {
  if (blockIdx.x < 64) {
    const int i = blockIdx.x * 256 + threadIdx.x;
    Qwb[i] = f2bf(Wq[i] * KSCALE);
    Vwb[i] = f2bf(Wv[i]);
  } else if (threadIdx.x < CC) {
    const int c = threadIdx.x;
    float s = 0.f;
    for (int o = 0; o < CC; ++o) s += Wk[(size_t)o * CC + c];
    csk[c] = s;
  }
}

// ---------------------------------------------------------------------------
// Kernel 1: QKV projection (proven).
//  Q[b][n][o] = (x.Wq^T + bq) * KSCALE   bf16 pixel-major
//  K[b][n][c] =  x[c][n]*csk[c] + bk[c]  bf16 pixel-major
//  V[b][o][n] =  x.Wv^T + bv             bf16 channel-major
// ---------------------------------------------------------------------------
__global__ __launch_bounds__(256, 2) void qkv_proj(
    const float* __restrict__ x,
    const unsigned short* __restrict__ Qwb, const float* __restrict__ bq,
    const float* __restrict__ csk, const float* __restrict__ bk,
    const unsigned short* __restrict__ Vwb, const float* __restrict__ bv,
    unsigned short* __restrict__ Q,
    unsigned short* __restrict__ K,
    unsigned short* __restrict__ V)
{
  const int b  = blockIdx.x & 7;
  const int n0 = (blockIdx.x >> 3) << 6;
  const int t  = threadIdx.x;
  const int lane = t & 63;
  const int w  = t >> 6;
  const int lq = lane & 15;
  const int g  = lane >> 4;

  __shared__ unsigned short xs[64][136];
  __shared__ unsigned short ks[64][136];
  __shared__ unsigned short vs[128][72];

  {
    const int n = t & 63;
    const float* xp = x + (size_t)b * (CC * NN) + n0 + n;
    for (int c = t >> 6; c < CC; c += 4) {
      const float xv = xp[(size_t)c * NN];
      xs[n][c] = f2bf(xv);
      ks[n][c] = f2bf(xv * csk[c] + bk[c]);
    }
  }
  __syncthreads();

  u16x8 a[4];
  {
    const unsigned short* ap = &xs[w * 16 + lq][g * 8];
    for (int ksl = 0; ksl < 4; ++ksl) a[ksl] = *(const u16x8*)(ap + ksl * 32);
  }

  for (int ot = 0; ot < 8; ++ot) {
    f32x4 aq = {0.f,0.f,0.f,0.f}, av = {0.f,0.f,0.f,0.f};
    const int o = ot * 16 + lq;
    const unsigned short* wq = Qwb + (size_t)o * CC + g * 8;
    const unsigned short* wv = Vwb + (size_t)o * CC + g * 8;
    for (int ksl = 0; ksl < 4; ++ksl) {
      aq = mfma16(a[ksl], *(const u16x8*)(wq + ksl * 32), aq);
      av = mfma16(a[ksl], *(const u16x8*)(wv + ksl * 32), av);
    }
    const float bqv = bq[o] * KSCALE, bvv = bv[o];
    for (int r = 0; r < 4; ++r) {
      const int nl = w * 16 + g * 4 + r;
      Q[((size_t)b * NN + n0 + nl) * CC + o] = f2bf(aq[r] + bqv);
      vs[o][nl] = f2bf(av[r] + bvv);
    }
  }
  __syncthreads();

  {
    unsigned short* kout = K + ((size_t)b * NN + n0) * CC;
    for (int i = t; i < 64 * 16; i += 256) {
      const int n = i >> 4, oc = (i & 15) * 8;
      *(uint4*)(kout + (size_t)n * CC + oc) = *(const uint4*)&ks[n][oc];
    }
  }
  {
    unsigned short* vout = V + (size_t)b * (CC * NN) + n0;
    for (int i = t; i < 128 * 32; i += 256) {
      const int c  = i >> 5;
      const int np = (i & 31) << 1;
      *(unsigned int*)(vout + (size_t)c * NN + np) = *(const unsigned int*)&vs[c][np];
    }
  }
}

// ---------------------------------------------------------------------------
// Kernel 2: flash attention partials, KV split 2-way (R5 structure, proven
// L2-friendly: FETCH ~12MB). Block: 512 thr = 8 waves x 16 q-rows; 64-key
// tiles, double-buffered. Changes vs R5:
//  (a) zero-conflict 4-bit XOR swizzles on K and V tiles (R7-measured 0 confl)
//  (b) NO Pt LDS round-trip: MFMA k-slot->key bijection remapped so the P
//      B-fragment is lane-local (8 cvt_pk words); V A-frag = 2x b64 reads.
// ---------------------------------------------------------------------------
__global__ __launch_bounds__(512, 4) void flash_attn(
    const unsigned short* __restrict__ Q,
    const unsigned short* __restrict__ K,
    const unsigned short* __restrict__ V,
    float* __restrict__ PO0, float* __restrict__ PO1,
    float2* __restrict__ PML)
{
  const int bid = blockIdx.x;
  const int b  = bid & 7;                    // batch -> XCD-local K/V/Q
  const int qb = (bid >> 3) & 31;
  const int sp = bid >> 8;                   // KV half 0/1
  const int kv0 = sp << 11;                  // 2048 keys per half
  const int t  = threadIdx.x;
  const int lane = t & 63;
  const int w  = t >> 6;                     // wave 0..7
  const int lq = lane & 15;
  const int g  = lane >> 4;
  const int q0w = (qb << 7) + (w << 4);      // 16 q-rows per wave

  __shared__ unsigned short KtL[2][64 * 128];   // 16KB each: [key][c], swizzled
  __shared__ unsigned short VlL[2][64 * 128];   // 16KB each: 2ch/256B row, swizzled

  // Q fragments (B-operand of swapped QK^T): col q = lq
  u16x8 qf[4];
  {
    const unsigned short* qp = Q + ((size_t)b * NN + q0w + lq) * CC + g * 8;
    #pragma unroll
    for (int ksl = 0; ksl < 4; ++ksl) qf[ksl] = *(const u16x8*)(qp + ksl * 32);
  }

  // ---- staging offsets (pre-inverse-swizzled source, linear LDS dest) ----
  const char* kgb = (const char*)(K + (size_t)b * NN * CC);   // 256B key rows
  const char* vgb = (const char*)(V + (size_t)b * CC * NN);   // 8192B channel rows
  int soK[2], soV[2], voC[2];
  #pragma unroll
  for (int j = 0; j < 2; ++j) {
    const int p = t * 16 + j * 8192;
    const int row = p >> 8;                    // 0..63
    const int off = (p & 255) ^ ((row & 15) << 4);
    soK[j] = (p & ~255) | off;
    const int ch = row * 2 + (off >> 7);
    voC[j] = ch * (NN * 2);
    soV[j] = off & 127;                        // key-byte within tile
  }
  const int p0 = t * 16;

  #define STAGE(nb, kv) do {                                                      \
    const char* kg_ = kgb + ((size_t)(kv) << 8);                                  \
    const char* vg_ = vgb + ((size_t)(kv) << 1);                                  \
    _Pragma("unroll")                                                             \
    for (int j = 0; j < 2; ++j)                                                   \
      __builtin_amdgcn_global_load_lds((gu32*)(kg_ + soK[j]),                     \
          (lu32*)((char*)KtL + (nb) * 16384 + p0 + j * 8192), 16, 0, 0);          \
    _Pragma("unroll")                                                             \
    for (int j = 0; j < 2; ++j)                                                   \
      __builtin_amdgcn_global_load_lds((gu32*)(vg_ + voC[j] + soV[j]),            \
          (lu32*)((char*)VlL + (nb) * 16384 + p0 + j * 8192), 16, 0, 0);          \
  } while (0)

  f32x4 oacc[8];
  #pragma unroll
  for (int i = 0; i < 8; ++i) oacc[i] = f32x4{0.f, 0.f, 0.f, 0.f};
  float m_run = -1e30f, l_run = 0.f;

  const int swzK = lq << 4;                    // K read swizzle: row&15 = lq

  STAGE(0, kv0);

  for (int tt = 0; tt < 32; ++tt) {
    const int cur = tt & 1;
    if (tt < 31) {
      STAGE(cur ^ 1, kv0 + (tt + 1) * 64);
      asm volatile("s_waitcnt vmcnt(4)" ::: "memory");   // current tile resident
    } else {
      asm volatile("s_waitcnt vmcnt(0)" ::: "memory");
    }
    __builtin_amdgcn_s_barrier();

    const char* kb  = (const char*)KtL + cur * 16384;
    const char* vbb = (const char*)VlL + cur * 16384;

    // ---- S^T = K . Q^T  (row = key, col = q) ----
    f32x4 s[4];
    #pragma unroll
    for (int kt = 0; kt < 4; ++kt) s[kt] = f32x4{0.f, 0.f, 0.f, 0.f};
    __builtin_amdgcn_s_setprio(1);
    #pragma unroll
    for (int kt = 0; kt < 4; ++kt) {
      const char* kp = kb + (kt * 16 + lq) * 256;
      #pragma unroll
      for (int ksl = 0; ksl < 4; ++ksl) {
        u16x8 kf = *(const u16x8*)(kp + ((ksl * 64 + g * 16) ^ swzK));
        s[kt] = mfma16(kf, qf[ksl], s[kt]);
      }
    }
    __builtin_amdgcn_s_setprio(0);

    // ---- online softmax (per q column; defer-max T13) ----
    float pm = fmaxf(fmaxf(s[0][0], s[0][1]), fmaxf(s[0][2], s[0][3]));
    #pragma unroll
    for (int kt = 1; kt < 4; ++kt)
      pm = fmaxf(pm, fmaxf(fmaxf(s[kt][0], s[kt][1]), fmaxf(s[kt][2], s[kt][3])));
    pm = fmaxf(pm, __shfl_xor(pm, 16));
    pm = fmaxf(pm, __shfl_xor(pm, 32));
    if (!__all(pm - m_run <= 8.0f)) {
      const float m_new = fmaxf(m_run, pm);
      const float alpha = exp2f(m_run - m_new);
      l_run *= alpha;
      #pragma unroll
      for (int i = 0; i < 8; ++i) {
        oacc[i][0] *= alpha; oacc[i][1] *= alpha;
        oacc[i][2] *= alpha; oacc[i][3] *= alpha;
      }
      m_run = m_new;
    }
    float lsum = 0.f;
    unsigned pkw[8];                    // P_{kt,h}: keys kt*16+g*4+{2h,2h+1}
    #pragma unroll
    for (int kt = 0; kt < 4; ++kt) {
      const float e0 = exp2f(s[kt][0] - m_run), e1 = exp2f(s[kt][1] - m_run);
      const float e2 = exp2f(s[kt][2] - m_run), e3 = exp2f(s[kt][3] - m_run);
      lsum += (e0 + e1) + (e2 + e3);
      pkw[kt * 2 + 0] = cvt_pk_bf16(e0, e1);
      pkw[kt * 2 + 1] = cvt_pk_bf16(e2, e3);
    }
    lsum += __shfl_xor(lsum, 16);
    lsum += __shfl_xor(lsum, 32);
    l_run += lsum;

    // ---- O^T += V^T . P^T  with lane-local slot->key remap ----
    // slice kk slot (g,j) -> key (2kk+(j>>2))*16 + g*4 + (j&3)
    // B-frag (P): {pkw[4kk], pkw[4kk+1], pkw[4kk+2], pkw[4kk+3]}  (lane-local!)
    // A-frag (V): b64 pairs at key-bytes 64kk+8g and 64kk+32+8g of row ch.
    u32x4 pw0 = {pkw[0], pkw[1], pkw[2], pkw[3]};
    u32x4 pw1 = {pkw[4], pkw[5], pkw[6], pkw[7]};
    const u16x8 pf0 = __builtin_bit_cast(u16x8, pw0);   // keys 0..31 (remapped)
    const u16x8 pf1 = __builtin_bit_cast(u16x8, pw1);   // keys 32..63 (remapped)
    __builtin_amdgcn_s_setprio(1);
    #pragma unroll
    for (int dt = 0; dt < 8; ++dt) {
      const int vrow = dt * 8 + (lq >> 1);               // ch = dt*16+lq, 2 ch/row
      const char* vp = vbb + vrow * 256;
      const int cb = (lq & 1) * 128;
      const int swzV = (vrow & 15) << 4;
      #pragma unroll
      for (int kk = 0; kk < 2; ++kk) {
        u16x4 lo = *(const u16x4*)(vp + ((cb + kk * 64 + g * 8) ^ swzV));
        u16x4 hi = *(const u16x4*)(vp + ((cb + kk * 64 + 32 + g * 8) ^ swzV));
        u16x8 vf = {lo[0], lo[1], lo[2], lo[3], hi[0], hi[1], hi[2], hi[3]};
        oacc[dt] = mfma16(vf, (kk == 0) ? pf0 : pf1, oacc[dt]);
      }
    }
    __builtin_amdgcn_s_setprio(0);
    asm volatile("s_waitcnt lgkmcnt(0)" ::: "memory"); // all reads of buf done
    __builtin_amdgcn_s_barrier();                      // safe to overwrite other buf
  }
  #undef STAGE

  // ---- epilogue: unnormalized fp32 partials, channel-major + (m,l) ----
  float* po = (sp ? PO1 : PO0) + (size_t)b * (CC * NN);
  const int n = q0w + lq;
  #pragma unroll
  for (int dt = 0; dt < 8; ++dt) {
    #pragma unroll
    for (int r = 0; r < 4; ++r) {
      const int c = dt * 16 + g * 4 + r;
      po[(size_t)c * NN + n] = oacc[dt][r];
    }
  }
  if (g == 0) PML[((size_t)sp * BB + b) * NN + n] = float2{m_run, l_run};
}

// ---------------------------------------------------------------------------
// Kernel 3: combine two KV-half partials + residual (R5 version, proven).
// out = x + (w0*O0 + w1*O1) / (w0*l0 + w1*l1),  w_s = exp2(m_s - max(m0,m1))
// ---------------------------------------------------------------------------
__global__ __launch_bounds__(256) void combine(
    const float* __restrict__ x, const float* __restrict__ PO1,
    const float2* __restrict__ PML, float* __restrict__ out)
{
  const size_t base = ((size_t)blockIdx.x * 256 + threadIdx.x) * 4;
  const int n = (int)(base & 4095);
  const int rest = (int)(base >> 12);
  const int b = rest >> 7;                    // rest = b*128 + c
  const float2* ml0 = PML + (size_t)b * NN + n;
  const float2* ml1 = PML + (size_t)(BB + b) * NN + n;
  float4 o0 = *(const float4*)(out + base);   // half 0 stored in d_out
  float4 o1 = *(const float4*)(PO1 + base);
  float4 xv = *(const float4*)(x + base);
  float4 r;
  #pragma unroll
  for (int i = 0; i < 4; ++i) {
    const float m0 = ml0[i].x, l0 = ml0[i].y;
    const float m1 = ml1[i].x, l1 = ml1[i].y;
    const float M = fmaxf(m0, m1);
    const float w0 = exp2f(m0 - M), w1 = exp2f(m1 - M);
    const float num = w0 * ((const float*)&o0)[i] + w1 * ((const float*)&o1)[i];
    const float den = w0 * l0 + w1 * l1;
    ((float*)&r)[i] = ((const float*)&xv)[i] + num / den;
  }
  *(float4*)(out + base) = r;
}

extern "C" void kernel_launch(void* const* d_in, const int* in_sizes, int n_in,
                              void* d_out, int out_size, void* d_ws, size_t ws_size,
                              hipStream_t stream) {
  (void)in_sizes; (void)n_in; (void)out_size; (void)ws_size;
  const float* x  = (const float*)d_in[0];
  const float* Wq = (const float*)d_in[1];
  const float* bq = (const float*)d_in[2];
  const float* Wk = (const float*)d_in[3];
  const float* bk = (const float*)d_in[4];
  const float* Wv = (const float*)d_in[5];
  const float* bv = (const float*)d_in[6];

  unsigned short* Q   = (unsigned short*)d_ws;                  // 8 MB
  unsigned short* K   = Q + (size_t)BB * NN * CC;               // 8 MB
  unsigned short* V   = K + (size_t)BB * NN * CC;               // 8 MB
  float* PO1          = (float*)(V + (size_t)BB * NN * CC);     // 16 MB fp32 partial (half 1)
  float2* PML         = (float2*)(PO1 + (size_t)BB * CC * NN);  // 512 KB stats
  unsigned short* Qwb = (unsigned short*)(PML + (size_t)2 * BB * NN); // 32 KB
  unsigned short* Vwb = Qwb + (size_t)CC * CC;                  // 32 KB
  float* csk = (float*)(Vwb + (size_t)CC * CC);                 // 512 B
  float* out = (float*)d_out;                                   // also fp32 partial 0

  prep<<<dim3(65), dim3(256), 0, stream>>>(Wq, Wv, Wk, Qwb, Vwb, csk);
  qkv_proj<<<dim3(BB * (NN / 64)), dim3(256), 0, stream>>>(x, Qwb, bq, csk, bk, Vwb, bv, Q, K, V);
  flash_attn<<<dim3(BB * 32 * 2), dim3(512), 0, stream>>>(Q, K, V, out, PO1, PML);
  combine<<<dim3((BB * CC * NN) / (256 * 4)), dim3(256), 0, stream>>>(x, PO1, PML, out);
}

// Round 11
// 142.430 us; speedup vs baseline: 1.9270x; 1.0217x over previous
//
#include <hip/hip_runtime.h>

#define BB 8
#define CC 128
#define NN 4096   // H*W = 64*64

typedef __bf16 bf16x8_t __attribute__((ext_vector_type(8)));
typedef unsigned short u16x8 __attribute__((ext_vector_type(8)));
typedef float f32x4 __attribute__((ext_vector_type(4)));
typedef unsigned int u32x4 __attribute__((ext_vector_type(4)));
typedef __attribute__((address_space(1))) const unsigned int gu32;
typedef __attribute__((address_space(3))) unsigned int lu32;

#define KSCALE 0.12753262456033348f   // (1/sqrt(128)) * log2(e)

__device__ __forceinline__ unsigned short f2bf(float f) {
  unsigned int u = __builtin_bit_cast(unsigned int, f);
  u += 0x7fffu + ((u >> 16) & 1u);          // RNE
  return (unsigned short)(u >> 16);
}

__device__ __forceinline__ unsigned int cvt_pk_bf16(float lo, float hi) {
  unsigned int r;
  asm("v_cvt_pk_bf16_f32 %0, %1, %2" : "=v"(r) : "v"(lo), "v"(hi));
  return r;
}

__device__ __forceinline__ f32x4 mfma16(u16x8 a, u16x8 b, f32x4 c) {
  return __builtin_amdgcn_mfma_f32_16x16x32_bf16(
      __builtin_bit_cast(bf16x8_t, a), __builtin_bit_cast(bf16x8_t, b), c, 0, 0, 0);
}

// ---------------------------------------------------------------------------
// Kernel 0: prep.  Blocks 0..63: Wq*KSCALE, Wv -> bf16.  Block 64: csk[c]=sum_o Wk[o][c]
// ---------------------------------------------------------------------------
__global__ void prep(const float* __restrict__ Wq, const float* __restrict__ Wv,
                     const float* __restrict__ Wk,
                     unsigned short* __restrict__ Qwb, unsigned short* __restrict__ Vwb,
                     float* __restrict__ csk) {
  if (blockIdx.x < 64) {
    const int i = blockIdx.x * 256 + threadIdx.x;
    Qwb[i] = f2bf(Wq[i] * KSCALE);
    Vwb[i] = f2bf(Wv[i]);
  } else if (threadIdx.x < CC) {
    const int c = threadIdx.x;
    float s = 0.f;
    for (int o = 0; o < CC; ++o) s += Wk[(size_t)o * CC + c];
    csk[c] = s;
  }
}

// ---------------------------------------------------------------------------
// Kernel 1: QKV projection (proven).
//  Q[b][n][o] = (x.Wq^T + bq) * KSCALE   bf16 pixel-major
//  K[b][n][c] =  x[c][n]*csk[c] + bk[c]  bf16 pixel-major
//  V[b][o][n] =  x.Wv^T + bv             bf16 channel-major
// ---------------------------------------------------------------------------
__global__ __launch_bounds__(256, 2) void qkv_proj(
    const float* __restrict__ x,
    const unsigned short* __restrict__ Qwb, const float* __restrict__ bq,
    const float* __restrict__ csk, const float* __restrict__ bk,
    const unsigned short* __restrict__ Vwb, const float* __restrict__ bv,
    unsigned short* __restrict__ Q,
    unsigned short* __restrict__ K,
    unsigned short* __restrict__ V)
{
  const int b  = blockIdx.x & 7;
  const int n0 = (blockIdx.x >> 3) << 6;
  const int t  = threadIdx.x;
  const int lane = t & 63;
  const int w  = t >> 6;
  const int lq = lane & 15;
  const int g  = lane >> 4;

  __shared__ unsigned short xs[64][136];
  __shared__ unsigned short ks[64][136];
  __shared__ unsigned short vs[128][72];

  {
    const int n = t & 63;
    const float* xp = x + (size_t)b * (CC * NN) + n0 + n;
    for (int c = t >> 6; c < CC; c += 4) {
      const float xv = xp[(size_t)c * NN];
      xs[n][c] = f2bf(xv);
      ks[n][c] = f2bf(xv * csk[c] + bk[c]);
    }
  }
  __syncthreads();

  u16x8 a[4];
  {
    const unsigned short* ap = &xs[w * 16 + lq][g * 8];
    for (int ksl = 0; ksl < 4; ++ksl) a[ksl] = *(const u16x8*)(ap + ksl * 32);
  }

  for (int ot = 0; ot < 8; ++ot) {
    f32x4 aq = {0.f,0.f,0.f,0.f}, av = {0.f,0.f,0.f,0.f};
    const int o = ot * 16 + lq;
    const unsigned short* wq = Qwb + (size_t)o * CC + g * 8;
    const unsigned short* wv = Vwb + (size_t)o * CC + g * 8;
    for (int ksl = 0; ksl < 4; ++ksl) {
      aq = mfma16(a[ksl], *(const u16x8*)(wq + ksl * 32), aq);
      av = mfma16(a[ksl], *(const u16x8*)(wv + ksl * 32), av);
    }
    const float bqv = bq[o] * KSCALE, bvv = bv[o];
    for (int r = 0; r < 4; ++r) {
      const int nl = w * 16 + g * 4 + r;
      Q[((size_t)b * NN + n0 + nl) * CC + o] = f2bf(aq[r] + bqv);
      vs[o][nl] = f2bf(av[r] + bvv);
    }
  }
  __syncthreads();

  {
    unsigned short* kout = K + ((size_t)b * NN + n0) * CC;
    for (int i = t; i < 64 * 16; i += 256) {
      const int n = i >> 4, oc = (i & 15) * 8;
      *(uint4*)(kout + (size_t)n * CC + oc) = *(const uint4*)&ks[n][oc];
    }
  }
  {
    unsigned short* vout = V + (size_t)b * (CC * NN) + n0;
    for (int i = t; i < 128 * 32; i += 256) {
      const int c  = i >> 5;
      const int np = (i & 31) << 1;
      *(unsigned int*)(vout + (size_t)c * NN + np) = *(const unsigned int*)&vs[c][np];
    }
  }
}

// ---------------------------------------------------------------------------
// Kernel 2: flash attention partials, KV split 2-way (R5/R10 structure,
// FETCH ~15MB proven). Block: 512 thr = 8 waves x 16 q-rows; 64-key tiles,
// double-buffered. vs R10: V LDS tile is KEY-PERMUTED so each PV A-fragment
// is ONE b128 read (key 32kk+16h+4g+r at row-byte 64kk+16g+8h+2r), staged
// via 4B-granular global_load_lds with pre-inverse-swizzled source.
// K path and lane-local P fragments unchanged.
// ---------------------------------------------------------------------------
__global__ __launch_bounds__(512, 4) void flash_attn(
    const unsigned short* __restrict__ Q,
    const unsigned short* __restrict__ K,
    const unsigned short* __restrict__ V,
    float* __restrict__ PO0, float* __restrict__ PO1,
    float2* __restrict__ PML)
{
  const int bid = blockIdx.x;
  const int b  = bid & 7;                    // batch -> XCD-local K/V/Q
  const int qb = (bid >> 3) & 31;
  const int sp = bid >> 8;                   // KV half 0/1
  const int kv0 = sp << 11;                  // 2048 keys per half
  const int t  = threadIdx.x;
  const int lane = t & 63;
  const int w  = t >> 6;                     // wave 0..7
  const int lq = lane & 15;
  const int g  = lane >> 4;
  const int q0w = (qb << 7) + (w << 4);      // 16 q-rows per wave

  __shared__ unsigned short KtL[2][64 * 128];   // 16KB each: [key][c], swizzled
  __shared__ unsigned short VlL[2][128 * 64];   // 16KB each: [ch][64keys permuted]

  // Q fragments (B-operand of swapped QK^T): col q = lq
  u16x8 qf[4];
  {
    const unsigned short* qp = Q + ((size_t)b * NN + q0w + lq) * CC + g * 8;
    #pragma unroll
    for (int ksl = 0; ksl < 4; ++ksl) qf[ksl] = *(const u16x8*)(qp + ksl * 32);
  }

  // ---- staging offsets (pre-inverse-swizzled source, linear LDS dest) ----
  const char* kgb = (const char*)(K + (size_t)b * NN * CC);   // 256B key rows
  const char* vgb = (const char*)(V + (size_t)b * CC * NN);   // 8192B channel rows
  int soK[2];
  #pragma unroll
  for (int j = 0; j < 2; ++j) {
    const int p = t * 16 + j * 8192;
    const int row = p >> 8;                    // 0..63
    soK[j] = (p & ~255) | ((p & 255) ^ ((row & 15) << 4));
  }
  // V: 8 chunks of 4B per thread. Physical LDS byte p -> channel ch=p>>7,
  // logical L = (p&127) ^ ((ch&7)<<4), global row-byte gb(L):
  //   L bits: b6=kk b5:4=g b3=h b2:1=r b0=parity -> gb = kk<<6|h<<5|g<<3|r<<1|par
  int vOff[8];
  #pragma unroll
  for (int n = 0; n < 8; ++n) {
    const int p = t * 4 + n * 2048;
    const int ch = p >> 7;
    const int L = (p & 127) ^ ((ch & 7) << 4);
    const int gb = (L & 7) | (((L >> 4) & 3) << 3) | (((L >> 3) & 1) << 5) | ((L >> 6) << 6);
    vOff[n] = ch * (NN * 2) + gb;
  }

  #define STAGE(nb, kv) do {                                                      \
    const char* kg_ = kgb + ((size_t)(kv) << 8);                                  \
    const char* vg_ = vgb + ((size_t)(kv) << 1);                                  \
    _Pragma("unroll")                                                             \
    for (int j = 0; j < 2; ++j)                                                   \
      __builtin_amdgcn_global_load_lds((gu32*)(kg_ + soK[j]),                     \
          (lu32*)((char*)KtL + (nb) * 16384 + t * 16 + j * 8192), 16, 0, 0);      \
    _Pragma("unroll")                                                             \
    for (int n = 0; n < 8; ++n)                                                   \
      __builtin_amdgcn_global_load_lds((gu32*)(vg_ + vOff[n]),                    \
          (lu32*)((char*)VlL + (nb) * 16384 + t * 4 + n * 2048), 4, 0, 0);        \
  } while (0)

  f32x4 oacc[8];
  #pragma unroll
  for (int i = 0; i < 8; ++i) oacc[i] = f32x4{0.f, 0.f, 0.f, 0.f};
  float m_run = -1e30f, l_run = 0.f;

  const int swzK  = lq << 4;                   // K read swizzle: row&15 = lq
  const int swzVl = (lq & 7) << 4;             // V read swizzle: ch&7 = lq&7

  STAGE(0, kv0);

  for (int tt = 0; tt < 32; ++tt) {
    const int cur = tt & 1;
    if (tt < 31) {
      STAGE(cur ^ 1, kv0 + (tt + 1) * 64);
      asm volatile("s_waitcnt vmcnt(10)" ::: "memory");  // current tile resident
    } else {
      asm volatile("s_waitcnt vmcnt(0)" ::: "memory");
    }
    __builtin_amdgcn_s_barrier();

    const char* kb  = (const char*)KtL + cur * 16384;
    const char* vbb = (const char*)VlL + cur * 16384;

    // ---- S^T = K . Q^T  (row = key, col = q) ----
    f32x4 s[4];
    #pragma unroll
    for (int kt = 0; kt < 4; ++kt) s[kt] = f32x4{0.f, 0.f, 0.f, 0.f};
    __builtin_amdgcn_s_setprio(1);
    #pragma unroll
    for (int kt = 0; kt < 4; ++kt) {
      const char* kp = kb + (kt * 16 + lq) * 256;
      #pragma unroll
      for (int ksl = 0; ksl < 4; ++ksl) {
        u16x8 kf = *(const u16x8*)(kp + ((ksl * 64 + g * 16) ^ swzK));
        s[kt] = mfma16(kf, qf[ksl], s[kt]);
      }
    }
    __builtin_amdgcn_s_setprio(0);

    // ---- online softmax (per q column; defer-max T13) ----
    float pm = fmaxf(fmaxf(s[0][0], s[0][1]), fmaxf(s[0][2], s[0][3]));
    #pragma unroll
    for (int kt = 1; kt < 4; ++kt)
      pm = fmaxf(pm, fmaxf(fmaxf(s[kt][0], s[kt][1]), fmaxf(s[kt][2], s[kt][3])));
    pm = fmaxf(pm, __shfl_xor(pm, 16));
    pm = fmaxf(pm, __shfl_xor(pm, 32));
    if (!__all(pm - m_run <= 8.0f)) {
      const float m_new = fmaxf(m_run, pm);
      const float alpha = exp2f(m_run - m_new);
      l_run *= alpha;
      #pragma unroll
      for (int i = 0; i < 8; ++i) {
        oacc[i][0] *= alpha; oacc[i][1] *= alpha;
        oacc[i][2] *= alpha; oacc[i][3] *= alpha;
      }
      m_run = m_new;
    }
    float lsum = 0.f;
    unsigned pkw[8];                    // P_{kt,h}: keys kt*16+g*4+{2h,2h+1}
    #pragma unroll
    for (int kt = 0; kt < 4; ++kt) {
      const float e0 = exp2f(s[kt][0] - m_run), e1 = exp2f(s[kt][1] - m_run);
      const float e2 = exp2f(s[kt][2] - m_run), e3 = exp2f(s[kt][3] - m_run);
      lsum += (e0 + e1) + (e2 + e3);
      pkw[kt * 2 + 0] = cvt_pk_bf16(e0, e1);
      pkw[kt * 2 + 1] = cvt_pk_bf16(e2, e3);
    }
    lsum += __shfl_xor(lsum, 16);
    lsum += __shfl_xor(lsum, 32);
    l_run += lsum;

    // ---- O^T += V^T . P^T : lane-local P; V = ONE b128 per slice ----
    // slice kk slot j -> key 32kk + 16(j>>2) + 4g + (j&3); V row-byte
    // 64kk + 16g + 2j matches exactly (key-permuted layout).
    u32x4 pw0 = {pkw[0], pkw[1], pkw[2], pkw[3]};
    u32x4 pw1 = {pkw[4], pkw[5], pkw[6], pkw[7]};
    const u16x8 pf0 = __builtin_bit_cast(u16x8, pw0);   // keys 0..31 (remapped)
    const u16x8 pf1 = __builtin_bit_cast(u16x8, pw1);   // keys 32..63 (remapped)
    __builtin_amdgcn_s_setprio(1);
    #pragma unroll
    for (int dt = 0; dt < 8; ++dt) {
      const char* vp = vbb + (dt * 16 + lq) * 128;       // ch = dt*16 + lq
      u16x8 vf0 = *(const u16x8*)(vp + ((g * 16) ^ swzVl));
      oacc[dt] = mfma16(vf0, pf0, oacc[dt]);
      u16x8 vf1 = *(const u16x8*)(vp + ((64 + g * 16) ^ swzVl));
      oacc[dt] = mfma16(vf1, pf1, oacc[dt]);
    }
    __builtin_amdgcn_s_setprio(0);
    asm volatile("s_waitcnt lgkmcnt(0)" ::: "memory"); // all reads of buf done
    __builtin_amdgcn_s_barrier();                      // safe to overwrite other buf
  }
  #undef STAGE

  // ---- epilogue: unnormalized fp32 partials, channel-major + (m,l) ----
  float* po = (sp ? PO1 : PO0) + (size_t)b * (CC * NN);
  const int n = q0w + lq;
  #pragma unroll
  for (int dt = 0; dt < 8; ++dt) {
    #pragma unroll
    for (int r = 0; r < 4; ++r) {
      const int c = dt * 16 + g * 4 + r;
      po[(size_t)c * NN + n] = oacc[dt][r];
    }
  }
  if (g == 0) PML[((size_t)sp * BB + b) * NN + n] = float2{m_run, l_run};
}

// ---------------------------------------------------------------------------
// Kernel 3: combine two KV-half partials + residual (proven).
// out = x + (w0*O0 + w1*O1) / (w0*l0 + w1*l1),  w_s = exp2(m_s - max(m0,m1))
// ---------------------------------------------------------------------------
__global__ __launch_bounds__(256) void combine(
    const float* __restrict__ x, const float* __restrict__ PO1,
    const float2* __restrict__ PML, float* __restrict__ out)
{
  const size_t base = ((size_t)blockIdx.x * 256 + threadIdx.x) * 4;
  const int n = (int)(base & 4095);
  const int rest = (int)(base >> 12);
  const int b = rest >> 7;                    // rest = b*128 + c
  const float2* ml0 = PML + (size_t)b * NN + n;
  const float2* ml1 = PML + (size_t)(BB + b) * NN + n;
  float4 o0 = *(const float4*)(out + base);   // half 0 stored in d_out
  float4 o1 = *(const float4*)(PO1 + base);
  float4 xv = *(const float4*)(x + base);
  float4 r;
  #pragma unroll
  for (int i = 0; i < 4; ++i) {
    const float m0 = ml0[i].x, l0 = ml0[i].y;
    const float m1 = ml1[i].x, l1 = ml1[i].y;
    const float M = fmaxf(m0, m1);
    const float w0 = exp2f(m0 - M), w1 = exp2f(m1 - M);
    const float num = w0 * ((const float*)&o0)[i] + w1 * ((const float*)&o1)[i];
    const float den = w0 * l0 + w1 * l1;
    ((float*)&r)[i] = ((const float*)&xv)[i] + num / den;
  }
  *(float4*)(out + base) = r;
}

extern "C" void kernel_launch(void* const* d_in, const int* in_sizes, int n_in,
                              void* d_out, int out_size, void* d_ws, size_t ws_size,
                              hipStream_t stream) {
  (void)in_sizes; (void)n_in; (void)out_size; (void)ws_size;
  const float* x  = (const float*)d_in[0];
  const float* Wq = (const float*)d_in[1];
  const float* bq = (const float*)d_in[2];
  const float* Wk = (const float*)d_in[3];
  const float* bk = (const float*)d_in[4];
  const float* Wv = (const float*)d_in[5];
  const float* bv = (const float*)d_in[6];

  unsigned short* Q   = (unsigned short*)d_ws;                  // 8 MB
  unsigned short* K   = Q + (size_t)BB * NN * CC;               // 8 MB
  unsigned short* V   = K + (size_t)BB * NN * CC;               // 8 MB
  float* PO1          = (float*)(V + (size_t)BB * NN * CC);     // 16 MB fp32 partial (half 1)
  float2* PML         = (float2*)(PO1 + (size_t)BB * CC * NN);  // 512 KB stats
  unsigned short* Qwb = (unsigned short*)(PML + (size_t)2 * BB * NN); // 32 KB
  unsigned short* Vwb = Qwb + (size_t)CC * CC;                  // 32 KB
  float* csk = (float*)(Vwb + (size_t)CC * CC);                 // 512 B
  float* out = (float*)d_out;                                   // also fp32 partial 0

  prep<<<dim3(65), dim3(256), 0, stream>>>(Wq, Wv, Wk, Qwb, Vwb, csk);
  qkv_proj<<<dim3(BB * (NN / 64)), dim3(256), 0, stream>>>(x, Qwb, bq, csk, bk, Vwb, bv, Q, K, V);
  flash_attn<<<dim3(BB * 32 * 2), dim3(512), 0, stream>>>(Q, K, V, out, PO1, PML);
  combine<<<dim3((BB * CC * NN) / (256 * 4)), dim3(256), 0, stream>>>(x, PO1, PML, out);
}